// Round 2
// baseline (334.004 us; speedup 1.0000x reference)
//
#include <hip/hip_runtime.h>
#include <stdint.h>

// Problem constants (SelfAttention: B=8, C=512, C8=64, W=2048)
#define B_  8
#define C_  512
#define CO_ 64
#define W_  2048
#define R_  640   // stacked projection rows: 64 q + 64 k + 512 v

typedef float f32x4 __attribute__((ext_vector_type(4)));
typedef __bf16 bf16x8 __attribute__((ext_vector_type(8)));
typedef unsigned short u16;
typedef u16 u16x8 __attribute__((ext_vector_type(8)));
typedef u16 u16x4 __attribute__((ext_vector_type(4)));

static __device__ __forceinline__ u16 f2b(float f){
  union { float f; unsigned u; } v; v.f = f;
  unsigned r = v.u + 0x7FFFu + ((v.u >> 16) & 1u);  // RNE
  return (u16)(r >> 16);
}
static __device__ __forceinline__ bf16x8 ldb(const u16* p){
  return __builtin_bit_cast(bf16x8, *(const u16x8*)p);
}
static __device__ __forceinline__ f32x4 mfma16(bf16x8 a, bf16x8 b, f32x4 c){
  return __builtin_amdgcn_mfma_f32_16x16x32_bf16(a, b, c, 0, 0, 0);
}

// ---------------- K0: stack + cast weights/bias to bf16 ----------------
__global__ __launch_bounds__(256) void prep_w(
    const float* __restrict__ Wq, const float* __restrict__ bq,
    const float* __restrict__ Wk, const float* __restrict__ bk,
    const float* __restrict__ Wv, const float* __restrict__ bv,
    u16* __restrict__ Wall, float* __restrict__ ball){
  int e = blockIdx.x * 256 + threadIdx.x;
  if (e < R_ * C_){
    int r = e >> 9, c = e & (C_ - 1);
    float w;
    if (r < 64)       w = Wq[r * C_ + c];
    else if (r < 128) w = Wk[(r - 64) * C_ + c];
    else              w = Wv[(r - 128) * C_ + c];
    Wall[e] = f2b(w);
  }
  if (e < R_){
    float bb;
    if (e < 64)       bb = bq[e];
    else if (e < 128) bb = bk[e - 64];
    else              bb = bv[e - 128];
    ball[e] = bb;
  }
}

// ---------------- K1: x [b][c][w] f32 -> xbT [b][w][c] bf16 ----------------
__global__ __launch_bounds__(256) void xpose(const float* __restrict__ x,
                                             u16* __restrict__ xbT){
  __shared__ float t[32][33];
  int b = blockIdx.z, c0 = blockIdx.y * 32, w0 = blockIdx.x * 32;
  int tx = threadIdx.x & 31, ty = threadIdx.x >> 5;   // ty 0..7
  const float* xb = x + (size_t)b * C_ * W_;
  #pragma unroll
  for (int k = 0; k < 4; k++)
    t[ty + k * 8][tx] = xb[(size_t)(c0 + ty + k * 8) * W_ + w0 + tx];
  __syncthreads();
  u16* ob = xbT + (size_t)b * W_ * C_;
  #pragma unroll
  for (int k = 0; k < 4; k++)
    ob[(size_t)(w0 + ty + k * 8) * C_ + c0 + tx] = f2b(t[tx][ty + k * 8]);
}

// ---------------- K2: fused projection GEMM ----------------
// Y[r][w] = sum_c Wall[r][c] * x[c][w] + ball[r], per batch.
// Outputs: r<64 -> q_t[w][r] ; 64<=r<128 -> kT[w][r-64] ; else v[r-128][w]
#define PADW 40
__global__ __launch_bounds__(256) void gemm_proj(
    const u16* __restrict__ Wall, const float* __restrict__ ball,
    const u16* __restrict__ xbT, u16* __restrict__ qt,
    u16* __restrict__ ktp, u16* __restrict__ vn){
  __shared__ u16 at[64][PADW];
  __shared__ u16 bt[64][PADW];
  int b = blockIdx.z;
  int m0 = blockIdx.y * 64, n0 = blockIdx.x * 64;
  int tid = threadIdx.x, lane = tid & 63, wid = tid >> 6;
  int wm = wid >> 1, wn = wid & 1;
  int g = lane >> 4, r = lane & 15;
  const u16* xb = xbT + (size_t)b * W_ * C_;
  f32x4 acc[2][2] = {};
  int srow = tid >> 2, sseg = (tid & 3) * 8;
  for (int kk = 0; kk < 16; kk++){
    int c0 = kk * 32;
    *(u16x8*)&at[srow][sseg] = *(const u16x8*)&Wall[(size_t)(m0 + srow) * C_ + c0 + sseg];
    *(u16x8*)&bt[srow][sseg] = *(const u16x8*)&xb[(size_t)(n0 + srow) * C_ + c0 + sseg];
    __syncthreads();
    bf16x8 a0 = ldb(&at[wm * 32 +  0 + r][g * 8]);
    bf16x8 a1 = ldb(&at[wm * 32 + 16 + r][g * 8]);
    bf16x8 b0 = ldb(&bt[wn * 32 +  0 + r][g * 8]);
    bf16x8 b1 = ldb(&bt[wn * 32 + 16 + r][g * 8]);
    acc[0][0] = mfma16(a0, b0, acc[0][0]);
    acc[0][1] = mfma16(a0, b1, acc[0][1]);
    acc[1][0] = mfma16(a1, b0, acc[1][0]);
    acc[1][1] = mfma16(a1, b1, acc[1][1]);
    __syncthreads();
  }
  // epilogue: bias + store in attention layouts
  #pragma unroll
  for (int i = 0; i < 2; i++){
    #pragma unroll
    for (int n = 0; n < 2; n++){
      int rbase = m0 + wm * 32 + i * 16 + g * 4;
      int wcol  = n0 + wn * 32 + n * 16 + r;
      if (m0 < 128){
        u16* base = (m0 == 0 ? qt : ktp) + (size_t)b * W_ * CO_;
        u16x4 pk;
        #pragma unroll
        for (int t = 0; t < 4; t++) pk[t] = f2b(acc[i][n][t] + ball[rbase + t]);
        *(u16x4*)&base[(size_t)wcol * CO_ + (rbase & 63)] = pk;
      } else {
        u16* vb = vn + (size_t)b * C_ * W_;
        #pragma unroll
        for (int t = 0; t < 4; t++)
          vb[(size_t)(rbase + t - 128) * W_ + wcol] = f2b(acc[i][n][t] + ball[rbase + t]);
      }
    }
  }
}

// ---------------- K3: barrier-free register flash attention ----------------
// 512 blocks x 256 thr. batch = bid&7 (XCD-L2 locality), igroup = bid>>3.
// Wave wc owns 32 i-rows (2 subtiles of 16) x 128 c-channels (8 ctiles).
// Swapped QK^T: S^T = mfma(K_frag, Q^T_frag) -> lane holds S^T[j=4g+t][i=r].
// P-pack: two 16-j subtiles' exp values form the K=32 PV B-frag in-lane.
__global__ __launch_bounds__(256) void attn2(
    const u16* __restrict__ qt, const u16* __restrict__ ktp,
    const u16* __restrict__ vn, const float* __restrict__ x,
    const float* __restrict__ gamma, float* __restrict__ out){
  int tid = threadIdx.x, lane = tid & 63, wc = tid >> 6;
  int bid = blockIdx.x;
  int b = bid & 7, i0 = (bid >> 3) * 32;
  int g = lane >> 4, r = lane & 15;
  const u16* qtb = qt  + (size_t)b * W_ * CO_;
  const u16* ktb = ktp + (size_t)b * W_ * CO_;
  const u16* vnb = vn  + (size_t)b * C_ * W_;
  int cbase = wc * 128;

  // hoist Q^T B-frags: fq[isub][h], k=o=h*32+8g+e, n=i=i0+isub*16+r
  bf16x8 fq[2][2];
  #pragma unroll
  for (int is = 0; is < 2; is++)
    #pragma unroll
    for (int h = 0; h < 2; h++)
      fq[is][h] = ldb(&qtb[(size_t)(i0 + is * 16 + r) * CO_ + h * 32 + g * 8]);

  f32x4 acc[2][8] = {};
  float m_r[2] = {-1e30f, -1e30f};
  float l_r[2] = {0.f, 0.f};

  #pragma unroll 2
  for (int j0 = 0; j0 < W_; j0 += 32){
    // K A-frags: fk[jsub][h]: m=j=j0+jsub*16+r, k=o=h*32+8g+e
    bf16x8 fk[2][2];
    #pragma unroll
    for (int js = 0; js < 2; js++)
      #pragma unroll
      for (int h = 0; h < 2; h++)
        fk[js][h] = ldb(&ktb[(size_t)(j0 + js * 16 + r) * CO_ + h * 32 + g * 8]);
    // V A-frags: fv[ct]: m=c=cbase+ct*16+r; k=8g+e -> j: e<4 -> j0+4g+e, e>=4 -> j0+16+4g+e-4
    u16x8 fv[8];
    #pragma unroll
    for (int ct = 0; ct < 8; ct++){
      const u16* vp = &vnb[(size_t)(cbase + ct * 16 + r) * W_ + j0 + 4 * g];
      u16x4 lo = *(const u16x4*)vp;
      u16x4 hi = *(const u16x4*)(vp + 16);
      fv[ct] = (u16x8){lo[0], lo[1], lo[2], lo[3], hi[0], hi[1], hi[2], hi[3]};
    }
    // per i-subtile: QK^T, online softmax, PV
    #pragma unroll
    for (int is = 0; is < 2; is++){
      f32x4 sA = {}, sB = {};
      sA = mfma16(fk[0][0], fq[is][0], sA);
      sA = mfma16(fk[0][1], fq[is][1], sA);
      sB = mfma16(fk[1][0], fq[is][0], sB);
      sB = mfma16(fk[1][1], fq[is][1], sB);
      // tile max over 32 j for this lane's i-column
      float tm = fmaxf(fmaxf(fmaxf(sA[0], sA[1]), fmaxf(sA[2], sA[3])),
                       fmaxf(fmaxf(sB[0], sB[1]), fmaxf(sB[2], sB[3])));
      tm = fmaxf(tm, __shfl_xor(tm, 16));
      tm = fmaxf(tm, __shfl_xor(tm, 32));
      // defer-max: rescale only when max grew past threshold
      if (__any(tm > m_r[is] + 8.f)){
        float mnew = fmaxf(m_r[is], tm);
        float al = __expf(m_r[is] - mnew);
        #pragma unroll
        for (int ct = 0; ct < 8; ct++)
          #pragma unroll
          for (int t = 0; t < 4; t++) acc[is][ct][t] *= al;
        l_r[is] *= al;
        m_r[is] = mnew;
      }
      float m = m_r[is];
      float pA[4], pB[4]; float ps = 0.f;
      #pragma unroll
      for (int t = 0; t < 4; t++){ pA[t] = __expf(sA[t] - m); ps += pA[t]; }
      #pragma unroll
      for (int t = 0; t < 4; t++){ pB[t] = __expf(sB[t] - m); ps += pB[t]; }
      ps += __shfl_xor(ps, 16);
      ps += __shfl_xor(ps, 32);
      l_r[is] += ps;
      u16x8 pk = (u16x8){f2b(pA[0]), f2b(pA[1]), f2b(pA[2]), f2b(pA[3]),
                         f2b(pB[0]), f2b(pB[1]), f2b(pB[2]), f2b(pB[3])};
      bf16x8 pf = __builtin_bit_cast(bf16x8, pk);
      #pragma unroll
      for (int ct = 0; ct < 8; ct++)
        acc[is][ct] = mfma16(__builtin_bit_cast(bf16x8, fv[ct]), pf, acc[is][ct]);
    }
  }
  // epilogue: out[c][i] = gamma * acc/l + x[c][i]
  float gm = gamma[0];
  const float* xb = x + (size_t)b * C_ * W_;
  float* ob = out + (size_t)b * C_ * W_;
  #pragma unroll
  for (int is = 0; is < 2; is++){
    float iv = 1.f / l_r[is];
    int icol = i0 + is * 16 + r;
    #pragma unroll
    for (int ct = 0; ct < 8; ct++){
      #pragma unroll
      for (int t = 0; t < 4; t++){
        int c = cbase + ct * 16 + g * 4 + t;
        ob[(size_t)c * W_ + icol] = gm * (acc[is][ct][t] * iv) + xb[(size_t)c * W_ + icol];
      }
    }
  }
}

extern "C" void kernel_launch(void* const* d_in, const int* in_sizes, int n_in,
                              void* d_out, int out_size, void* d_ws, size_t ws_size,
                              hipStream_t stream) {
  const float* x     = (const float*)d_in[0];
  const float* Wq    = (const float*)d_in[1];
  const float* bq    = (const float*)d_in[2];
  const float* Wk    = (const float*)d_in[3];
  const float* bk    = (const float*)d_in[4];
  const float* Wv    = (const float*)d_in[5];
  const float* bv    = (const float*)d_in[6];
  const float* gamma = (const float*)d_in[7];
  float* out = (float*)d_out;
  char* ws = (char*)d_ws;
  // workspace layout (~38.4 MB total)
  u16*   Wall = (u16*)  (ws + 0);         // 640*512*2        = 655360
  float* ball = (float*)(ws + 655360);    // 640*4            = 2560
  u16*   xbT  = (u16*)  (ws + 657920);    // 8*2048*512*2     = 16777216
  u16*   qt   = (u16*)  (ws + 17435136);  // 8*2048*64*2      = 2097152
  u16*   ktp  = (u16*)  (ws + 19532288);  // 8*2048*64*2      = 2097152
  u16*   vn   = (u16*)  (ws + 21629440);  // 8*512*2048*2     = 16777216

  prep_w<<<dim3(1280), dim3(256), 0, stream>>>(Wq, bq, Wk, bk, Wv, bv, Wall, ball);
  xpose<<<dim3(64, 16, 8), dim3(256), 0, stream>>>(x, xbT);
  gemm_proj<<<dim3(32, 10, 8), dim3(256), 0, stream>>>(Wall, ball, xbT, qt, ktp, vn);
  attn2<<<dim3(512), dim3(256), 0, stream>>>(qt, ktp, vn, x, gamma, out);
}

// Round 3
// 279.821 us; speedup vs baseline: 1.1936x; 1.1936x over previous
//
#include <hip/hip_runtime.h>
#include <stdint.h>

// Problem constants (SelfAttention: B=8, C=512, C8=64, W=2048)
#define B_  8
#define C_  512
#define CO_ 64
#define W_  2048
#define R_  640   // stacked projection rows: 64 q + 64 k + 512 v

typedef float f32x4 __attribute__((ext_vector_type(4)));
typedef __bf16 bf16x8 __attribute__((ext_vector_type(8)));
typedef unsigned short u16;
typedef u16 u16x8 __attribute__((ext_vector_type(8)));
typedef u16 u16x4 __attribute__((ext_vector_type(4)));

static __device__ __forceinline__ u16 f2b(float f){
  union { float f; unsigned u; } v; v.f = f;
  unsigned r = v.u + 0x7FFFu + ((v.u >> 16) & 1u);  // RNE
  return (u16)(r >> 16);
}
static __device__ __forceinline__ bf16x8 ldb(const u16* p){
  return __builtin_bit_cast(bf16x8, *(const u16x8*)p);
}
static __device__ __forceinline__ f32x4 mfma16(bf16x8 a, bf16x8 b, f32x4 c){
  return __builtin_amdgcn_mfma_f32_16x16x32_bf16(a, b, c, 0, 0, 0);
}

// ---------------- K0: stack + cast weights/bias to bf16 ----------------
__global__ __launch_bounds__(256) void prep_w(
    const float* __restrict__ Wq, const float* __restrict__ bq,
    const float* __restrict__ Wk, const float* __restrict__ bk,
    const float* __restrict__ Wv, const float* __restrict__ bv,
    u16* __restrict__ Wall, float* __restrict__ ball){
  int e = blockIdx.x * 256 + threadIdx.x;
  if (e < R_ * C_){
    int r = e >> 9, c = e & (C_ - 1);
    float w;
    if (r < 64)       w = Wq[r * C_ + c];
    else if (r < 128) w = Wk[(r - 64) * C_ + c];
    else              w = Wv[(r - 128) * C_ + c];
    Wall[e] = f2b(w);
  }
  if (e < R_){
    float bb;
    if (e < 64)       bb = bq[e];
    else if (e < 128) bb = bk[e - 64];
    else              bb = bv[e - 128];
    ball[e] = bb;
  }
}

// ---------------- K1: x [b][c][w] f32 -> xbT [b][w][c] bf16 ----------------
__global__ __launch_bounds__(256) void xpose(const float* __restrict__ x,
                                             u16* __restrict__ xbT){
  __shared__ float t[32][33];
  int b = blockIdx.z, c0 = blockIdx.y * 32, w0 = blockIdx.x * 32;
  int tx = threadIdx.x & 31, ty = threadIdx.x >> 5;   // ty 0..7
  const float* xb = x + (size_t)b * C_ * W_;
  #pragma unroll
  for (int k = 0; k < 4; k++)
    t[ty + k * 8][tx] = xb[(size_t)(c0 + ty + k * 8) * W_ + w0 + tx];
  __syncthreads();
  u16* ob = xbT + (size_t)b * W_ * C_;
  #pragma unroll
  for (int k = 0; k < 4; k++)
    ob[(size_t)(w0 + ty + k * 8) * C_ + c0 + tx] = f2b(t[tx][ty + k * 8]);
}

// ---------------- K2: fused projection GEMM ----------------
// Y[r][w] = sum_c Wall[r][c] * x[c][w] + ball[r], per batch.
// r<64 -> q_t[w][r] ; 64<=r<128 -> kT[w][r-64] ; else v_perm[r-128][P(w)]
// P(w): within each 32-col block, position p = 8*g + 4*hi + t for
// w32 = hi*16 + g*4 + t  -> matches PV mfma A-frag k-layout (k=8g+e).
#define PADW 40
__global__ __launch_bounds__(256) void gemm_proj(
    const u16* __restrict__ Wall, const float* __restrict__ ball,
    const u16* __restrict__ xbT, u16* __restrict__ qt,
    u16* __restrict__ ktp, u16* __restrict__ vn){
  __shared__ u16 at[64][PADW];
  __shared__ u16 bt[64][PADW];
  int b = blockIdx.z;
  int m0 = blockIdx.y * 64, n0 = blockIdx.x * 64;
  int tid = threadIdx.x, lane = tid & 63, wid = tid >> 6;
  int wm = wid >> 1, wn = wid & 1;
  int g = lane >> 4, r = lane & 15;
  const u16* xb = xbT + (size_t)b * W_ * C_;
  f32x4 acc[2][2] = {};
  int srow = tid >> 2, sseg = (tid & 3) * 8;
  for (int kk = 0; kk < 16; kk++){
    int c0 = kk * 32;
    *(u16x8*)&at[srow][sseg] = *(const u16x8*)&Wall[(size_t)(m0 + srow) * C_ + c0 + sseg];
    *(u16x8*)&bt[srow][sseg] = *(const u16x8*)&xb[(size_t)(n0 + srow) * C_ + c0 + sseg];
    __syncthreads();
    bf16x8 a0 = ldb(&at[wm * 32 +  0 + r][g * 8]);
    bf16x8 a1 = ldb(&at[wm * 32 + 16 + r][g * 8]);
    bf16x8 b0 = ldb(&bt[wn * 32 +  0 + r][g * 8]);
    bf16x8 b1 = ldb(&bt[wn * 32 + 16 + r][g * 8]);
    acc[0][0] = mfma16(a0, b0, acc[0][0]);
    acc[0][1] = mfma16(a0, b1, acc[0][1]);
    acc[1][0] = mfma16(a1, b0, acc[1][0]);
    acc[1][1] = mfma16(a1, b1, acc[1][1]);
    __syncthreads();
  }
  // epilogue: bias + store in attention layouts
  #pragma unroll
  for (int i = 0; i < 2; i++){
    #pragma unroll
    for (int n = 0; n < 2; n++){
      int rbase = m0 + wm * 32 + i * 16 + g * 4;
      int wcol  = n0 + wn * 32 + n * 16 + r;
      if (m0 < 128){
        u16* base = (m0 == 0 ? qt : ktp) + (size_t)b * W_ * CO_;
        u16x4 pk;
        #pragma unroll
        for (int t = 0; t < 4; t++) pk[t] = f2b(acc[i][n][t] + ball[rbase + t]);
        *(u16x4*)&base[(size_t)wcol * CO_ + (rbase & 63)] = pk;
      } else {
        u16* vb = vn + (size_t)b * C_ * W_;
        int w32 = wcol & 31;
        int p32 = ((w32 & 12) << 1) | (((w32 >> 4) & 1) << 2) | (w32 & 3);
        int pcol = (wcol & ~31) | p32;
        #pragma unroll
        for (int t = 0; t < 4; t++)
          vb[(size_t)(rbase + t - 128) * W_ + pcol] = f2b(acc[i][n][t] + ball[rbase + t]);
      }
    }
  }
}

// ---------------- K3: barrier-free register flash attention v3 ----------------
// 1024 blocks x 256 thr (4096 independent waves). b = bid&7 (XCD-L2 locality).
// Wave: 32 i-rows (2 subtiles) x 64 c-channels (4 ctiles). All frags are
// single dwordx4 loads (V via permuted layout). acc 32 AGPR; ~105 unified regs.
__global__ __launch_bounds__(256, 4) void attn3(
    const u16* __restrict__ qt, const u16* __restrict__ ktp,
    const u16* __restrict__ vp, const float* __restrict__ x,
    const float* __restrict__ gamma, float* __restrict__ out){
  int tid = threadIdx.x, lane = tid & 63, wv = tid >> 6;
  int bid = blockIdx.x;
  int b = bid & 7;
  int u = bid >> 3;                  // 0..127
  int i0 = (u & 63) * 32;
  int cbase = (u >> 6) * 256 + wv * 64;
  int g = lane >> 4, r = lane & 15;
  const u16* qtb = qt  + (size_t)b * W_ * CO_;
  const u16* ktb = ktp + (size_t)b * W_ * CO_;
  const u16* vpb = vp  + (size_t)b * C_ * W_;

  // Q^T B-frags: n=i=i0+is*16+r, k=o=h*32+8g+e
  bf16x8 fq[2][2];
  #pragma unroll
  for (int is = 0; is < 2; is++)
    #pragma unroll
    for (int h = 0; h < 2; h++)
      fq[is][h] = ldb(&qtb[(size_t)(i0 + is * 16 + r) * CO_ + h * 32 + g * 8]);

  f32x4 acc[2][4] = {};
  float m_r[2] = {-1e30f, -1e30f};
  float l_r[2] = {0.f, 0.f};

  for (int j0 = 0; j0 < W_; j0 += 32){
    // K A-frags: m=j=j0+js*16+r, k=o=h*32+8g+e
    bf16x8 fk[2][2];
    #pragma unroll
    for (int js = 0; js < 2; js++)
      #pragma unroll
      for (int h = 0; h < 2; h++)
        fk[js][h] = ldb(&ktb[(size_t)(j0 + js * 16 + r) * CO_ + h * 32 + g * 8]);
    // V A-frags (permuted layout): one dwordx4 per ctile, k=8g+e -> j per P()
    bf16x8 fv[4];
    #pragma unroll
    for (int ct = 0; ct < 4; ct++)
      fv[ct] = ldb(&vpb[(size_t)(cbase + ct * 16 + r) * W_ + j0 + g * 8]);
    // per i-subtile: QK^T (swapped), online softmax, PV
    #pragma unroll
    for (int is = 0; is < 2; is++){
      f32x4 sA = {}, sB = {};
      sA = mfma16(fk[0][0], fq[is][0], sA);
      sA = mfma16(fk[0][1], fq[is][1], sA);
      sB = mfma16(fk[1][0], fq[is][0], sB);
      sB = mfma16(fk[1][1], fq[is][1], sB);
      // tile max over 32 j for this lane's i-column
      float tm = fmaxf(fmaxf(fmaxf(sA[0], sA[1]), fmaxf(sA[2], sA[3])),
                       fmaxf(fmaxf(sB[0], sB[1]), fmaxf(sB[2], sB[3])));
      tm = fmaxf(tm, __shfl_xor(tm, 16));
      tm = fmaxf(tm, __shfl_xor(tm, 32));
      // defer-max: rescale only when max grew past threshold (T13)
      if (__any(tm > m_r[is] + 8.f)){
        float mnew = fmaxf(m_r[is], tm);
        float al = __expf(m_r[is] - mnew);
        #pragma unroll
        for (int ct = 0; ct < 4; ct++)
          #pragma unroll
          for (int t = 0; t < 4; t++) acc[is][ct][t] *= al;
        l_r[is] *= al;
        m_r[is] = mnew;
      }
      float m = m_r[is];
      float pA[4], pB[4]; float ps = 0.f;
      #pragma unroll
      for (int t = 0; t < 4; t++){ pA[t] = __expf(sA[t] - m); ps += pA[t]; }
      #pragma unroll
      for (int t = 0; t < 4; t++){ pB[t] = __expf(sB[t] - m); ps += pB[t]; }
      ps += __shfl_xor(ps, 16);
      ps += __shfl_xor(ps, 32);
      l_r[is] += ps;
      bf16x8 pf;
      #pragma unroll
      for (int t = 0; t < 4; t++){ pf[t] = (__bf16)pA[t]; pf[4 + t] = (__bf16)pB[t]; }
      #pragma unroll
      for (int ct = 0; ct < 4; ct++)
        acc[is][ct] = mfma16(fv[ct], pf, acc[is][ct]);
    }
  }
  // epilogue: out[c][i] = gamma * acc/l + x[c][i]
  float gm = gamma[0];
  const float* xb = x + (size_t)b * C_ * W_;
  float* ob = out + (size_t)b * C_ * W_;
  #pragma unroll
  for (int is = 0; is < 2; is++){
    float iv = 1.f / l_r[is];
    int icol = i0 + is * 16 + r;
    #pragma unroll
    for (int ct = 0; ct < 4; ct++){
      #pragma unroll
      for (int t = 0; t < 4; t++){
        int c = cbase + ct * 16 + g * 4 + t;
        ob[(size_t)c * W_ + icol] = gm * (acc[is][ct][t] * iv) + xb[(size_t)c * W_ + icol];
      }
    }
  }
}

extern "C" void kernel_launch(void* const* d_in, const int* in_sizes, int n_in,
                              void* d_out, int out_size, void* d_ws, size_t ws_size,
                              hipStream_t stream) {
  const float* x     = (const float*)d_in[0];
  const float* Wq    = (const float*)d_in[1];
  const float* bq    = (const float*)d_in[2];
  const float* Wk    = (const float*)d_in[3];
  const float* bk    = (const float*)d_in[4];
  const float* Wv    = (const float*)d_in[5];
  const float* bv    = (const float*)d_in[6];
  const float* gamma = (const float*)d_in[7];
  float* out = (float*)d_out;
  char* ws = (char*)d_ws;
  // workspace layout (~38.4 MB total)
  u16*   Wall = (u16*)  (ws + 0);         // 640*512*2        = 655360
  float* ball = (float*)(ws + 655360);    // 640*4            = 2560
  u16*   xbT  = (u16*)  (ws + 657920);    // 8*2048*512*2     = 16777216
  u16*   qt   = (u16*)  (ws + 17435136);  // 8*2048*64*2      = 2097152
  u16*   ktp  = (u16*)  (ws + 19532288);  // 8*2048*64*2      = 2097152
  u16*   vn   = (u16*)  (ws + 21629440);  // 8*512*2048*2     = 16777216

  prep_w<<<dim3(1280), dim3(256), 0, stream>>>(Wq, bq, Wk, bk, Wv, bv, Wall, ball);
  xpose<<<dim3(64, 16, 8), dim3(256), 0, stream>>>(x, xbT);
  gemm_proj<<<dim3(32, 10, 8), dim3(256), 0, stream>>>(Wall, ball, xbT, qt, ktp, vn);
  attn3<<<dim3(1024), dim3(256), 0, stream>>>(qt, ktp, vn, x, gamma, out);
}